// Round 1
// baseline (319.100 us; speedup 1.0000x reference)
//
#include <hip/hip_runtime.h>
#include <hip/hip_bf16.h>

// Problem constants
#define NB    8
#define CIN   64
#define HH    128
#define WW    128
#define COUT  64
#define KTAP  9
#define HOUT  128
#define WOUT  128
#define HW    (HH * WW)          // 16384
#define WQ_ELEMS (CIN * KTAP * COUT)  // 36864

// ---------------- Kernel 1: per-tensor scale = max(|w|)/127 ----------------
__global__ __launch_bounds__(256) void scale_kernel(const float* __restrict__ w,
                                                    float* __restrict__ scale_out) {
    float m = 0.f;
    for (int i = threadIdx.x; i < COUT * CIN * KTAP; i += 256)
        m = fmaxf(m, fabsf(w[i]));
    // wave (64-lane) reduce
    #pragma unroll
    for (int off = 32; off > 0; off >>= 1)
        m = fmaxf(m, __shfl_down(m, off));
    __shared__ float sm[4];
    if ((threadIdx.x & 63) == 0) sm[threadIdx.x >> 6] = m;
    __syncthreads();
    if (threadIdx.x == 0) {
        m = fmaxf(fmaxf(sm[0], sm[1]), fmaxf(sm[2], sm[3]));
        scale_out[0] = fmaxf(m, 1e-8f) / 127.f;
    }
}

// ------------- Kernel 2: quantize + transpose to wq[(c*9+k)*64 + o] -------------
__global__ __launch_bounds__(256) void quant_kernel(const float* __restrict__ w,
                                                    const float* __restrict__ scale_p,
                                                    float* __restrict__ wq) {
    int t = blockIdx.x * 256 + threadIdx.x;   // 0 .. 36863
    if (t >= WQ_ELEMS) return;
    float scale = scale_p[0];
    int o  = t & 63;
    int ck = t >> 6;
    int c  = ck / 9;
    int k  = ck - 9 * c;
    float v = w[(o * CIN + c) * KTAP + k];    // weight[o][c][ky][kx]
    float q = rintf(v / scale);               // jnp.round = round-half-even = rintf
    q = fminf(fmaxf(q, -128.f), 127.f);
    wq[t] = q * scale;
}

// ---------------- Kernel 3: deformable conv main ----------------
// One thread per output pixel; 64 fp32 accumulators (all COUT channels).
// wq reads are wave-uniform -> scalar loads; x reads are bilinear gathers.
__global__ __launch_bounds__(256) void deform_main(const float* __restrict__ x,
                                                   const float* __restrict__ offset,
                                                   const float* __restrict__ wq,
                                                   float* __restrict__ out) {
    const int t = threadIdx.x;
    const int b = blockIdx.x;            // 512 blocks
    const int n = b >> 6;                // 64 blocks per image
    const int p = ((b & 63) << 8) + t;   // pixel index in [0, 16384)
    const int ho = p >> 7;
    const int wo = p & 127;

    const float* xn   = x + n * (CIN * HW);
    const float* offn = offset + n * (2 * KTAP * HW) + p;

    float acc[COUT];
    #pragma unroll
    for (int o = 0; o < COUT; o++) acc[o] = 0.f;

    for (int k = 0; k < KTAP; k++) {
        const int ky = k / 3;
        const int kx = k - 3 * ky;
        const float py = (float)(ho - 1 + ky) + offn[(2 * k) * HW];
        const float px = (float)(wo - 1 + kx) + offn[(2 * k + 1) * HW];
        const float fy = floorf(py);
        const float fx = floorf(px);
        const int y0 = (int)fy;
        const int x0 = (int)fx;
        const float dy = py - fy;
        const float dx = px - fx;

        const int y1 = y0 + 1;
        const int x1 = x0 + 1;
        const bool vy0 = (y0 >= 0) && (y0 < HH);
        const bool vy1 = (y1 >= 0) && (y1 < HH);
        const bool vx0 = (x0 >= 0) && (x0 < WW);
        const bool vx1 = (x1 >= 0) && (x1 < WW);
        const int y0c = min(max(y0, 0), HH - 1);
        const int y1c = min(max(y1, 0), HH - 1);
        const int x0c = min(max(x0, 0), WW - 1);
        const int x1c = min(max(x1, 0), WW - 1);

        float w00 = (1.f - dy) * (1.f - dx) * ((vy0 && vx0) ? 1.f : 0.f);
        float w01 = (1.f - dy) * dx         * ((vy0 && vx1) ? 1.f : 0.f);
        float w10 = dy * (1.f - dx)         * ((vy1 && vx0) ? 1.f : 0.f);
        float w11 = dy * dx                 * ((vy1 && vx1) ? 1.f : 0.f);

        const int i00 = y0c * WW + x0c;
        const int i01 = y0c * WW + x1c;
        const int i10 = y1c * WW + x0c;
        const int i11 = y1c * WW + x1c;

        #pragma unroll 2
        for (int c = 0; c < CIN; c++) {
            const float* xc = xn + c * HW;
            const float s = xc[i00] * w00 + xc[i01] * w01 +
                            xc[i10] * w10 + xc[i11] * w11;
            const float* wck = wq + (c * 9 + k) * 64;  // wave-uniform -> s_load
            #pragma unroll
            for (int o = 0; o < COUT; o++)
                acc[o] = fmaf(s, wck[o], acc[o]);
        }
    }

    float* outp = out + n * (COUT * HW) + p;
    #pragma unroll
    for (int o = 0; o < COUT; o++)
        outp[o * HW] = acc[o];
}

extern "C" void kernel_launch(void* const* d_in, const int* in_sizes, int n_in,
                              void* d_out, int out_size, void* d_ws, size_t ws_size,
                              hipStream_t stream) {
    const float* x      = (const float*)d_in[0];  // [8,64,128,128]
    const float* offset = (const float*)d_in[1];  // [8,18,128,128]
    const float* weight = (const float*)d_in[2];  // [64,64,3,3]
    float* out = (float*)d_out;                   // [8,64,128,128]

    float* scale_p = (float*)d_ws;                // 1 float
    float* wq      = (float*)d_ws + 64;           // 36864 floats, aligned

    scale_kernel<<<1, 256, 0, stream>>>(weight, scale_p);
    quant_kernel<<<(WQ_ELEMS + 255) / 256, 256, 0, stream>>>(weight, scale_p, wq);
    deform_main<<<NB * (HW / 256), 256, 0, stream>>>(x, offset, wq, out);
}

// Round 2
// 145.335 us; speedup vs baseline: 2.1956x; 2.1956x over previous
//
#include <hip/hip_runtime.h>
#include <hip/hip_bf16.h>

// Problem constants
#define NB    8
#define CCH   64      // CIN = COUT = 64
#define HH    128
#define WW    128
#define KTAP  9
#define HW    (HH * WW)            // 16384
#define KDIM  (CCH * KTAP)         // 576
#define KSTEPS 18                  // 576 / 32
#define LDA   72                   // padded A row (bf16 elems), 64+8

typedef __attribute__((ext_vector_type(8))) short bf16x8;
typedef __attribute__((ext_vector_type(4))) float f32x4;

// RNE float->bf16 pair pack (inputs finite)
__device__ inline unsigned int pack_bf16(float a, float b) {
    unsigned int ua = __float_as_uint(a);
    unsigned int ub = __float_as_uint(b);
    ua += 0x7fffu + ((ua >> 16) & 1u);
    ub += 0x7fffu + ((ub >> 16) & 1u);
    return (ua >> 16) | (ub & 0xffff0000u);
}

__device__ inline void cvt8(uint4 u, float* f) {
    f[0] = __uint_as_float(u.x << 16); f[1] = __uint_as_float(u.x & 0xffff0000u);
    f[2] = __uint_as_float(u.y << 16); f[3] = __uint_as_float(u.y & 0xffff0000u);
    f[4] = __uint_as_float(u.z << 16); f[5] = __uint_as_float(u.z & 0xffff0000u);
    f[6] = __uint_as_float(u.w << 16); f[7] = __uint_as_float(u.w & 0xffff0000u);
}

// ---------- K1: maxabs(w) via per-wave reduce + atomicMax on uint ----------
__global__ __launch_bounds__(256) void maxabs_kernel(const float* __restrict__ w,
                                                     unsigned int* __restrict__ out) {
    unsigned int m = 0;
    int i = blockIdx.x * 1024 + threadIdx.x;   // 36 blocks cover 36864
    #pragma unroll
    for (int r = 0; r < 4; r++) {
        m = max(m, __float_as_uint(w[i]) & 0x7fffffffu);
        i += 256;
    }
    #pragma unroll
    for (int off = 32; off > 0; off >>= 1)
        m = max(m, (unsigned int)__shfl_down(m, off));
    if ((threadIdx.x & 63) == 0) atomicMax(out, m);
}

// ---------- K2: quantize + swizzle weights into MFMA B-fragment order ----------
// bq layout: uint4 index t = (nt*18 + s)*64 + lane ; 8 bf16 per lane:
//   elem j -> B[k = s*32 + (lane>>4)*8 + j][o = nt*16 + (lane&15)], k = tap*64 + c
__global__ __launch_bounds__(256) void quant_frag_kernel(const float* __restrict__ w,
                                                         const unsigned int* __restrict__ maxabs_u,
                                                         uint4* __restrict__ bq) {
    int t = blockIdx.x * 256 + threadIdx.x;    // 0..4607
    if (t >= 4608) return;
    float m = __uint_as_float(maxabs_u[0]);
    float scale = fmaxf(m, 1e-8f) / 127.f;
    int nt  = t / (KSTEPS * 64);
    int rem = t - nt * (KSTEPS * 64);
    int s    = rem >> 6;
    int lane = rem & 63;
    int quad = lane >> 4, n16 = lane & 15;
    int o = nt * 16 + n16;
    unsigned int u[4];
    #pragma unroll
    for (int jj = 0; jj < 4; jj++) {
        float q[2];
        #pragma unroll
        for (int h = 0; h < 2; h++) {
            int k   = s * 32 + quad * 8 + 2 * jj + h;
            int c   = k & 63;
            int tap = k >> 6;
            float v  = w[(o * CCH + c) * KTAP + tap];
            float qq = rintf(v / scale);
            q[h] = fminf(fmaxf(qq, -128.f), 127.f) * scale;
        }
        u[jj] = pack_bf16(q[0], q[1]);
    }
    bq[t] = make_uint4(u[0], u[1], u[2], u[3]);
}

// ---------- K3: transpose x NCHW fp32 -> xt NHWC bf16 ----------
__global__ __launch_bounds__(256) void transpose_kernel(const float* __restrict__ x,
                                                        unsigned int* __restrict__ xt32) {
    __shared__ float tile[64][65];
    const int t = threadIdx.x;
    const int n = blockIdx.x >> 8;
    const int pbase = (blockIdx.x & 255) * 64;
    #pragma unroll
    for (int i = 0; i < 16; i++) {
        int idx = i * 256 + t;
        int c = idx >> 6, pp = idx & 63;
        tile[c][pp] = x[((size_t)(n * CCH + c)) * HW + pbase + pp];
    }
    __syncthreads();
    #pragma unroll
    for (int j = 0; j < 8; j++) {
        int idx = j * 256 + t;
        int pp = idx >> 5, cp = idx & 31;
        xt32[((size_t)(n * HW + pbase + pp)) * 32 + cp] =
            pack_bf16(tile[2 * cp][pp], tile[2 * cp + 1][pp]);
    }
}

// ---------- K4: fused deformable-sample + MFMA GEMM ----------
// Block: 64 pixels x 64 outputs. 4 waves, wave w = n-tile w (16 outputs, all 64 px).
__global__ __launch_bounds__(256) void deform_mfma(const unsigned short* __restrict__ xt,
                                                   const float* __restrict__ offset,
                                                   const uint4* __restrict__ bq,
                                                   float* __restrict__ out) {
    __shared__ unsigned short Abuf[2][64 * LDA];   // 2 x 9216 B

    const int t    = threadIdx.x;
    const int wid  = t >> 6;
    const int lane = t & 63;
    const int quad = lane >> 4, n16 = lane & 15;
    const int bid  = blockIdx.x;
    const int n    = bid & 7;                 // XCD swizzle: image -> XCD
    const int px0  = (bid >> 3) * 64;
    const int p_local = t >> 2;               // 0..63, pixel within tile
    const int cq      = (t & 3) * 16;         // channel base for this thread
    const int ppx = px0 + p_local;
    const int ho  = ppx >> 7, wo = ppx & 127;

    const unsigned short* xtn = xt + (size_t)n * HW * CCH;
    const float* offn = offset + (size_t)n * 2 * KTAP * HW;

    // Preload this wave's B slab (18 K-steps x 16B/lane)
    uint4 bfrag[KSTEPS];
    #pragma unroll
    for (int s = 0; s < KSTEPS; s++)
        bfrag[s] = bq[(wid * KSTEPS + s) * 64 + lane];

    f32x4 acc[4];
    #pragma unroll
    for (int mt = 0; mt < 4; mt++) acc[mt] = (f32x4){0.f, 0.f, 0.f, 0.f};

    auto build = [&](int tap, int buf) {
        const int ky = tap / 3;
        const int kx = tap - 3 * ky;
        const float offy = offn[(2 * tap) * HW + ppx];
        const float offx = offn[(2 * tap + 1) * HW + ppx];
        const float py  = (float)(ho - 1 + ky) + offy;
        const float pxf = (float)(wo - 1 + kx) + offx;
        const float fy = floorf(py), fx = floorf(pxf);
        const int y0 = (int)fy, x0 = (int)fx;
        const float dy = py - fy, dx = pxf - fx;
        const int y1 = y0 + 1, x1 = x0 + 1;
        const bool vy0 = (y0 >= 0) && (y0 < HH);
        const bool vy1 = (y1 >= 0) && (y1 < HH);
        const bool vx0 = (x0 >= 0) && (x0 < WW);
        const bool vx1 = (x1 >= 0) && (x1 < WW);
        const int y0c = min(max(y0, 0), HH - 1);
        const int y1c = min(max(y1, 0), HH - 1);
        const int x0c = min(max(x0, 0), WW - 1);
        const int x1c = min(max(x1, 0), WW - 1);
        const float w00 = (1.f - dy) * (1.f - dx) * ((vy0 && vx0) ? 1.f : 0.f);
        const float w01 = (1.f - dy) * dx         * ((vy0 && vx1) ? 1.f : 0.f);
        const float w10 = dy * (1.f - dx)         * ((vy1 && vx0) ? 1.f : 0.f);
        const float w11 = dy * dx                 * ((vy1 && vx1) ? 1.f : 0.f);

        const unsigned short* p00 = xtn + (y0c * WW + x0c) * CCH + cq;
        const unsigned short* p01 = xtn + (y0c * WW + x1c) * CCH + cq;
        const unsigned short* p10 = xtn + (y1c * WW + x0c) * CCH + cq;
        const unsigned short* p11 = xtn + (y1c * WW + x1c) * CCH + cq;
        uint4 a00 = *(const uint4*)p00, b00 = *(const uint4*)(p00 + 8);
        uint4 a01 = *(const uint4*)p01, b01 = *(const uint4*)(p01 + 8);
        uint4 a10 = *(const uint4*)p10, b10 = *(const uint4*)(p10 + 8);
        uint4 a11 = *(const uint4*)p11, b11 = *(const uint4*)(p11 + 8);

        float s[16], f[16];
        cvt8(a00, f); cvt8(b00, f + 8);
        #pragma unroll
        for (int i = 0; i < 16; i++) s[i] = f[i] * w00;
        cvt8(a01, f); cvt8(b01, f + 8);
        #pragma unroll
        for (int i = 0; i < 16; i++) s[i] = fmaf(f[i], w01, s[i]);
        cvt8(a10, f); cvt8(b10, f + 8);
        #pragma unroll
        for (int i = 0; i < 16; i++) s[i] = fmaf(f[i], w10, s[i]);
        cvt8(a11, f); cvt8(b11, f + 8);
        #pragma unroll
        for (int i = 0; i < 16; i++) s[i] = fmaf(f[i], w11, s[i]);

        unsigned int o8[8];
        #pragma unroll
        for (int i = 0; i < 8; i++) o8[i] = pack_bf16(s[2 * i], s[2 * i + 1]);
        unsigned short* dst = &Abuf[buf][p_local * LDA + cq];
        *(uint4*)dst       = make_uint4(o8[0], o8[1], o8[2], o8[3]);
        *(uint4*)(dst + 8) = make_uint4(o8[4], o8[5], o8[6], o8[7]);
    };

    auto mma_tap = [&](int tap, int buf) {
        #pragma unroll
        for (int sl = 0; sl < 2; sl++) {
            const int sg = tap * 2 + sl;
            bf16x8 b = *(bf16x8*)&bfrag[sg];
            #pragma unroll
            for (int mt = 0; mt < 4; mt++) {
                const unsigned short* src =
                    &Abuf[buf][(mt * 16 + n16) * LDA + sl * 32 + quad * 8];
                bf16x8 a = *(const bf16x8*)src;
                acc[mt] = __builtin_amdgcn_mfma_f32_16x16x32_bf16(a, b, acc[mt], 0, 0, 0);
            }
        }
    };

    build(0, 0);
    __syncthreads();
    for (int tap = 0; tap < KTAP; tap++) {
        if (tap < KTAP - 1) build(tap + 1, (tap + 1) & 1);
        mma_tap(tap, tap & 1);
        __syncthreads();
    }

    // Epilogue: D row = quad*4+r (pixel), col = n16 (output channel)
    const int o = wid * 16 + n16;
    #pragma unroll
    for (int mt = 0; mt < 4; mt++) {
        float4 v = make_float4(acc[mt].x, acc[mt].y, acc[mt].z, acc[mt].w);
        float* dst = out + ((size_t)(n * CCH + o)) * HW + px0 + mt * 16 + quad * 4;
        *(float4*)dst = v;
    }
}

extern "C" void kernel_launch(void* const* d_in, const int* in_sizes, int n_in,
                              void* d_out, int out_size, void* d_ws, size_t ws_size,
                              hipStream_t stream) {
    const float* x      = (const float*)d_in[0];   // [8,64,128,128]
    const float* offset = (const float*)d_in[1];   // [8,18,128,128]
    const float* weight = (const float*)d_in[2];   // [64,64,3,3]
    float* out = (float*)d_out;                    // [8,64,128,128]

    unsigned char* ws = (unsigned char*)d_ws;
    unsigned int* maxabs_u = (unsigned int*)ws;              // 4 B
    uint4*        bq       = (uint4*)(ws + 1024);            // 73728 B
    unsigned int* xt32     = (unsigned int*)(ws + 131072);   // 16 MB (bf16 NHWC)
    unsigned short* xt     = (unsigned short*)xt32;

    hipMemsetAsync(maxabs_u, 0, 4, stream);
    maxabs_kernel<<<36, 256, 0, stream>>>(weight, maxabs_u);
    quant_frag_kernel<<<18, 256, 0, stream>>>(weight, maxabs_u, bq);
    transpose_kernel<<<NB * (HW / 64), 256, 0, stream>>>(x, xt32);
    deform_mfma<<<NB * (HW / 64), 256, 0, stream>>>(xt, offset, bq, out);
}